// Round 6
// baseline (77.291 us; speedup 1.0000x reference)
//
#include <hip/hip_runtime.h>
#include <math.h>

#ifndef M_PI
#define M_PI 3.14159265358979323846
#endif

#define NPTS 8192
#define KCOMP 64
#define BLK 256
#define IPB 16               // i's per block
#define NB (NPTS / IPB)      // 512 blocks (2 per CU)
#define SLICES 16            // j-slices per i (one per thread group)
#define C4 (NPTS / 4)        // 2048 float4 in x
#define CPT (C4 / SLICES)    // 128 float4 per thread

// Module-load zero-initialized; advances by EXACTLY NB per call, so the
// last-arriver test (old & (NB-1)) == NB-1 is invariant across the
// correctness call, graph capture, and every replay. No memset needed.
__device__ int g_ctr;

// Force the single-instruction hardware exp2 (v_exp_f32, ~1 ulp).
__device__ __forceinline__ float fexp2(float a) {
#if __has_builtin(__builtin_amdgcn_exp2f)
  return __builtin_amdgcn_exp2f(a);
#else
  float r;
  asm("v_exp_f32 %0, %1" : "=v"(r) : "v"(a));
  return r;
#endif
}

// One dispatch, 512 blocks x 256. Block b owns i in [b*16, b*16+16):
//  - stage all 8192 x (pre-scaled) in LDS (32 KB)
//  - thread (il = t&15, p = t>>4): KDE over j-slice p (512 j, float4-interleaved,
//    bank-conflict-free) + mixture components 4p..4p+3, folded with opposite
//    signs into ONE partial (diff_i is linear in both sums)
//  - LDS-reduce 16 slices -> diff_i, square, wave-reduce -> msep[b]
//  - one agent-scope ACQ_REL fetch_add; last arriver sums 512 msep -> out[0]
__global__ __launch_bounds__(BLK) void fused_kernel(
    const float* __restrict__ x,
    const float* __restrict__ logits,
    const float* __restrict__ means,
    const float* __restrict__ log_vars,
    float* __restrict__ msep,    // [NB] in ws
    float* __restrict__ out) {
  __shared__ alignas(16) float xs[NPTS];
  __shared__ float sm[KCOMP], sa[KCOMP], sq[KCOMP];
  __shared__ float red[BLK];
  __shared__ float wsum[4];
  __shared__ int sflag;

  const int t  = threadIdx.x;
  const int b  = blockIdx.x;
  const int il = t & (IPB - 1);
  const int p  = t >> 4;

  // kern = exp(-0.5 d^2 / bw^2) = 2^(-(s*d)^2), s = sqrt(8192 * log2(e))
  const float s = sqrtf(8192.0f * 1.44269504088896340736f);

  // stage all of x (scaled) into LDS: 8 coalesced float4 per thread
  const float4* xg4 = reinterpret_cast<const float4*>(x);
  float4* xs4w = reinterpret_cast<float4*>(xs);
#pragma unroll
  for (int k = 0; k < C4 / BLK; ++k) {
    float4 v = xg4[t + k * BLK];
    xs4w[t + k * BLK] = make_float4(v.x * s, v.y * s, v.z * s, v.w * s);
  }

  if (t < KCOMP) {               // wave 0: softmax over K=64 via shfl
    float l = logits[t];
    float m = l;
#pragma unroll
    for (int off = 32; off > 0; off >>= 1)
      m = fmaxf(m, __shfl_xor(m, off));
    float e = expf(l - m);
    float ssum = e;
#pragma unroll
    for (int off = 32; off > 0; off >>= 1)
      ssum += __shfl_xor(ssum, off);
    float w = e / ssum;
    float var = expf(log_vars[t]);
    sm[t] = means[t];
    sa[t] = w * rsqrtf(2.0f * (float)M_PI * var);   // amplitude
    sq[t] = 0.72134752044448170368f / var;          // 0.5*log2(e)/var
  }
  __syncthreads();

  const int i  = b * IPB + il;
  const float u = xs[i];         // pre-scaled own point (from LDS)

  // KDE over slice p: float4 chunks c*16+p (wave: 4 p's -> 16 distinct banks)
  float a0 = 0.f, a1 = 0.f, a2 = 0.f, a3 = 0.f;
  const float4* xs4 = reinterpret_cast<const float4*>(xs);
#pragma unroll 4
  for (int c = 0; c < CPT; ++c) {
    float4 v = xs4[c * SLICES + p];
    float d0 = u - v.x;
    float d1 = u - v.y;
    float d2 = u - v.z;
    float d3 = u - v.w;
    a0 += fexp2(-(d0 * d0));     // v_sub + v_mul + v_exp(-src) + v_add
    a1 += fexp2(-(d1 * d1));
    a2 += fexp2(-(d2 * d2));
    a3 += fexp2(-(d3 * d3));
  }
  float kde = (a0 + a1) + (a2 + a3);

  // mixture components 4p..4p+3 for the same i
  const float xi = x[i];
  float mixp = 0.f;
#pragma unroll
  for (int c = 0; c < 4; ++c) {
    int k = p * 4 + c;
    float d = xi - sm[k];
    mixp += sa[k] * fexp2(-(sq[k] * d) * d);
  }

  // data_pdf = kde_sum / (sqrt(2*pi)*bw*N), bw*N = 64
  const float inv_norm = 1.0f / (2.50662827463100050242f * 64.0f);
  red[t] = mixp - kde * inv_norm;   // per-(i,slice) diff partial
  __syncthreads();

  if (t < IPB) {                 // lanes 0..15 of wave 0
    float diff = 0.f;
#pragma unroll
    for (int q = 0; q < SLICES; ++q)
      diff += red[t + (q << 4)];
    float v = diff * diff;
#pragma unroll
    for (int off = 8; off > 0; off >>= 1)
      v += __shfl_xor(v, off);   // reduce lanes 0..15
    if (t == 0) msep[b] = v;     // plain store; released by the RMW below
  }

  if (t == 0) {
    int old = __hip_atomic_fetch_add(&g_ctr, 1,
                                     __ATOMIC_ACQ_REL, __HIP_MEMORY_SCOPE_AGENT);
    sflag = ((old & (NB - 1)) == (NB - 1));   // last arriver
  }
  __syncthreads();
  if (!sflag) return;

  // ---- winner: all msep visible (t0's acquire invalidated this CU's L1) ----
  float v2 = msep[t] + msep[t + BLK];
#pragma unroll
  for (int off = 32; off > 0; off >>= 1)
    v2 += __shfl_xor(v2, off);
  if ((t & 63) == 0) wsum[t >> 6] = v2;
  __syncthreads();
  if (t == 0) out[0] = (wsum[0] + wsum[1]) + (wsum[2] + wsum[3]);
}

extern "C" void kernel_launch(void* const* d_in, const int* in_sizes, int n_in,
                              void* d_out, int out_size, void* d_ws, size_t ws_size,
                              hipStream_t stream) {
  const float* x     = (const float*)d_in[0];
  const float* wl    = (const float*)d_in[1];
  const float* means = (const float*)d_in[2];
  const float* lv    = (const float*)d_in[3];
  float* out  = (float*)d_out;
  float* msep = (float*)d_ws;   // NB floats, fully overwritten every call

  fused_kernel<<<dim3(NB), dim3(BLK), 0, stream>>>(
      x, wl, means, lv, msep, out);
}